// Round 6
// baseline (211.129 us; speedup 1.0000x reference)
//
#include <hip/hip_runtime.h>
#include <hip/hip_fp16.h>

// Trilinear sampler: im [B,H,W,D,C] f32, coords [B,N,3] f32 (y,x,z), out [B,N,C] f32.
// B=2, H=W=D=128, C=2, N=H*W*D.
//
// R13 post-mortem: sample halves = 47.3us each, FETCH 143MB each (perfect
//   split, no refetch) -> 3.65 TB/s random-line ceiling triply confirmed.
//   Repack STILL absent from top-5 (< 46.9us). Unaccounted ~112us.
// R14 (this round): sample split into 4 quarter-dispatches (~23.6us each) so
//   the top-5 cutoff drops below repack's likely duration -> repack appears
//   WITH counters (FETCH/WRITE/VALUBusy) next round. Repack kernel untouched.
//   Predict: quarters 23.5-24.5us each (FETCH ~72MB each), total 207+-4.
//   If repack absent (<23.6us): kernels sum <120us vs 207 total -> rest is
//   fixed harness overhead -> declare floor.

constexpr int Hc = 128, Wc = 128, Dc = 128;
constexpr int Npts = Hc * Wc * Dc;                 // 2^21 points per batch
constexpr int CELLS = 1 << 21;                     // 128^3 records per batch (16B each)
constexpr size_t REC_BYTES = (size_t)2 * CELLS * 16;   // 67,108,864 (both batches)
constexpr int PTS_PER_THREAD = 4;
constexpr int NTHREADS = 2 * Npts / PTS_PER_THREAD;
constexpr int BLOCK = 256;

typedef float nfloat4 __attribute__((ext_vector_type(4)));   // native vec for nt builtins

// 16-byte payload with only 8-byte alignment guarantee (fallback path)
struct __attribute__((packed, aligned(8))) f4u { float x, y, z, w; };

// ---------------- repack: im (fp32) -> per-(cy,cx,z) 4-corner fp16 records ----------------
// record layout (16B): hh[0]=(y,x) hh[1]=(y,x1) hh[2]=(y1,x) hh[3]=(y1,x1), each (c0,c1).
// Block = 4x4 (cy,cx) tile x HALF z (64): stage 5x5 rows' z-half, emit
// 16 x 1KB column bursts. 4096 blocks; zh = bid&1 so block pairs share im rows in L2.
__global__ __launch_bounds__(BLOCK)
void TrilinearSampler_34059090658011_repack(const float* __restrict__ im,
                                            nfloat4* __restrict__ rec) {
    __shared__ __align__(16) float2 srow[25][64];          // 5x5 rows x 64 z, 12.8 KB

    const int tid  = threadIdx.x;
    const int bid  = blockIdx.x;                           // b(1) | ty(5) | tx(5) | zh(1)
    const int zh   = bid & 1;
    const int tile = bid >> 1;
    const int b    = tile >> 10;
    const int ty4  = ((tile >> 5) & 31) << 2;              // tile origin y
    const int tx4  = (tile & 31) << 2;                     // tile origin x
    const int z0   = zh << 6;                              // z-half origin

    const float* __restrict__ imb = im + ((size_t)b << 22);   // 2^21 voxels * 2ch floats

    // ---- stage: 25 rows x 32 x 16B pieces = 800 loads, coalesced per row ----
    for (int p = tid; p < 800; p += BLOCK) {
        const int u_ = p >> 5;                             // row slot 0..24
        const int q  = p & 31;                             // 16B piece within z-half
        const int ry = (u_ * 13) >> 6;                     // u_/5
        const int rx = u_ - ry * 5;
        const int gy = ::min(ty4 + ry, 127);               // clamp = border replicate
        const int gx = ::min(tx4 + rx, 127);
        const nfloat4 v = *reinterpret_cast<const nfloat4*>(
            imb + ((size_t)(gy * 128 + gx) << 8) + (z0 << 1) + (q << 2));
        reinterpret_cast<nfloat4*>(srow)[u_ * 32 + q] = v;
    }
    __syncthreads();

    // ---- assemble: thread builds record (column cc, height z0+zl); 4 cols/iter ----
    const int zl = tid & 63;
    const int cp = tid >> 6;                               // column group 0..3
#pragma unroll
    for (int k = 0; k < 4; ++k) {
        const int cc = k * 4 + cp;                         // 0..15
        const int yy = cc >> 2, xx = cc & 3;
        const int s00 = yy * 5 + xx;
        const float2 f0 = srow[s00][zl];                   // (y,  x )
        const float2 f1 = srow[s00 + 1][zl];               // (y,  x1)
        const float2 f2 = srow[s00 + 5][zl];               // (y1, x )
        const float2 f3 = srow[s00 + 6][zl];               // (y1, x1)

        union { __half2 hh[4]; nfloat4 f; } u;
        u.hh[0] = __floats2half2_rn(f0.x, f0.y);
        u.hh[1] = __floats2half2_rn(f1.x, f1.y);
        u.hh[2] = __floats2half2_rn(f2.x, f2.y);
        u.hh[3] = __floats2half2_rn(f3.x, f3.y);

        const int gy = ty4 + yy, gx = tx4 + xx;
        // column base contiguous in z: each wave stores 1KB burst
        rec[((((size_t)b << 14) + (gy << 7) + gx) << 7) + z0 + zl] = u.f;
    }
}

// ---------------- sample pass: two contiguous 16B records (32B) per point ----------------
__global__ __launch_bounds__(BLOCK)
void TrilinearSampler_34059090658011_sample(const nfloat4* __restrict__ rec,
                                            const float* __restrict__ coords,
                                            float* __restrict__ out,
                                            int t0) {
    const int t = t0 + blockIdx.x * BLOCK + threadIdx.x;   // one thread = 4 points

    const nfloat4* __restrict__ c4 = reinterpret_cast<const nfloat4*>(coords);
    const nfloat4 ca = __builtin_nontemporal_load(&c4[3 * t + 0]);
    const nfloat4 cb = __builtin_nontemporal_load(&c4[3 * t + 1]);
    const nfloat4 cc = __builtin_nontemporal_load(&c4[3 * t + 2]);

    const int b = (t * PTS_PER_THREAD) >> 21;              // wave-uniform
    const nfloat4* __restrict__ rb = rec + ((size_t)b << 21);   // CELLS records/batch

    const float ys[4] = {ca.x, ca.w, cb.z, cc.y};
    const float xs[4] = {ca.y, cb.x, cb.w, cc.z};
    const float zs[4] = {ca.z, cb.y, cc.x, cc.w};

    // phase 1: cells + weights
    int   cidx[4];
    float dxs[4], dys[4], dzs[4];
#pragma unroll
    for (int i = 0; i < 4; ++i) {
        const float x = xs[i] + 1.0f;
        const float y = ys[i] + 1.0f;
        const float z = zs[i] + 1.0f;
        const int x0 = (int)floorf(x);
        const int y0 = (int)floorf(y);
        const int z0 = (int)floorf(z);
        dxs[i] = (float)(x0 + 1) - x;                      // interior guaranteed
        dys[i] = (float)(y0 + 1) - y;
        dzs[i] = (float)(z0 + 1) - z;
        const int ix0 = ::min(::max(x0 - 1, 0), Wc - 2);
        const int iy0 = ::min(::max(y0 - 1, 0), Hc - 2);
        const int izb = ::min(::max(z0 - 1, 0), Dc - 2);
        cidx[i] = ((iy0 << 7) | ix0) << 7 | izb;
    }

    // phase 2: 8 loads (2 contiguous 16B records per point)
    nfloat4 lo[4], hi[4];
#pragma unroll
    for (int i = 0; i < 4; ++i) {
        lo[i] = rb[cidx[i]];                               // z0 plane
        hi[i] = rb[cidx[i] + 1];                           // z1 plane
    }

    // phase 3: combine
    float res[8];
#pragma unroll
    for (int i = 0; i < 4; ++i) {
        const __half2* h = reinterpret_cast<const __half2*>(&lo[i]);   // z0 plane
        const __half2* g = reinterpret_cast<const __half2*>(&hi[i]);   // z1 plane
        const float2 f0 = __half22float2(h[0]);   // z0 (y0,x0)
        const float2 f1 = __half22float2(h[1]);   // z0 (y0,x1)
        const float2 f2 = __half22float2(h[2]);   // z0 (y1,x0)
        const float2 f3 = __half22float2(h[3]);   // z0 (y1,x1)
        const float2 g0 = __half22float2(g[0]);   // z1 (y0,x0)
        const float2 g1 = __half22float2(g[1]);   // z1 (y0,x1)
        const float2 g2 = __half22float2(g[2]);   // z1 (y1,x0)
        const float2 g3 = __half22float2(g[3]);   // z1 (y1,x1)

        const float dx = dxs[i], dy = dys[i], dz = dzs[i];
        const float w00 = dy * dx,          w01 = dy * (1.0f - dx);
        const float w10 = (1.0f - dy) * dx, w11 = (1.0f - dy) * (1.0f - dx);
        const float wz0 = dz, wz1 = 1.0f - dz;

        const float a0 = w00 * f0.x + w01 * f1.x + w10 * f2.x + w11 * f3.x;  // z0, c0
        const float b0 = w00 * f0.y + w01 * f1.y + w10 * f2.y + w11 * f3.y;  // z0, c1
        const float a1 = w00 * g0.x + w01 * g1.x + w10 * g2.x + w11 * g3.x;  // z1, c0
        const float b1 = w00 * g0.y + w01 * g1.y + w10 * g2.y + w11 * g3.y;  // z1, c1

        res[2 * i + 0] = wz0 * a0 + wz1 * a1;
        res[2 * i + 1] = wz0 * b0 + wz1 * b1;
    }

    nfloat4* __restrict__ o4 = reinterpret_cast<nfloat4*>(out);
    const nfloat4 r0 = {res[0], res[1], res[2], res[3]};
    const nfloat4 r1 = {res[4], res[5], res[6], res[7]};
    __builtin_nontemporal_store(r0, &o4[2 * t + 0]);
    __builtin_nontemporal_store(r1, &o4[2 * t + 1]);
}

// ---------------- fallback (direct fp32 path, both batches) ----------------
__global__ __launch_bounds__(BLOCK)
void TrilinearSampler_34059090658011_kernel(const float* __restrict__ im,
                                            const float* __restrict__ coords,
                                            float* __restrict__ out) {
    const int t = blockIdx.x * BLOCK + threadIdx.x;

    const float4* __restrict__ c4 = reinterpret_cast<const float4*>(coords);
    const float4 ca = c4[3 * t + 0];
    const float4 cb = c4[3 * t + 1];
    const float4 cc = c4[3 * t + 2];

    const int b = (t * PTS_PER_THREAD) >> 21;
    const char* __restrict__ imb =
        reinterpret_cast<const char*>(im) + (size_t)b * (size_t)Npts * 8u;

    const float ys[4] = {ca.x, ca.w, cb.z, cc.y};
    const float xs[4] = {ca.y, cb.x, cb.w, cc.z};
    const float zs[4] = {ca.z, cb.y, cc.x, cc.w};

    int   off[16];
    float w00[4], w01[4], w10[4], w11[4], wz0[4], wz1[4];
#pragma unroll
    for (int i = 0; i < 4; ++i) {
        const float x = xs[i] + 1.0f;
        const float y = ys[i] + 1.0f;
        const float z = zs[i] + 1.0f;
        const int x0 = (int)floorf(x);
        const int y0 = (int)floorf(y);
        const int z0 = (int)floorf(z);
        const float dx = (float)(x0 + 1) - x;
        const float dy = (float)(y0 + 1) - y;
        const float dz = (float)(z0 + 1) - z;
        const int ix0 = ::min(::max(x0 - 1, 0), Wc - 2);
        const int iy0 = ::min(::max(y0 - 1, 0), Hc - 2);
        const int izb = ::min(::max(z0 - 1, 0), Dc - 2);
        w00[i] = dx * dy;
        w01[i] = dx * (1.0f - dy);
        w10[i] = (1.0f - dx) * dy;
        w11[i] = (1.0f - dx) * (1.0f - dy);
        wz0[i] = dz;
        wz1[i] = 1.0f - dz;
        const int r00 = ((iy0 * Wc + ix0) * Dc + izb) * 8;
        off[4 * i + 0] = r00;
        off[4 * i + 1] = r00 + Wc * Dc * 8;
        off[4 * i + 2] = r00 + Dc * 8;
        off[4 * i + 3] = r00 + (Wc + 1) * Dc * 8;
    }

    f4u g[16];
#pragma unroll
    for (int j = 0; j < 16; ++j)
        g[j] = *reinterpret_cast<const f4u*>(imb + off[j]);

    float res[8];
#pragma unroll
    for (int i = 0; i < 4; ++i) {
        const f4u g00 = g[4 * i + 0];
        const f4u g01 = g[4 * i + 1];
        const f4u g10 = g[4 * i + 2];
        const f4u g11 = g[4 * i + 3];
        const float az0c0 = w00[i] * g00.x + w01[i] * g01.x + w10[i] * g10.x + w11[i] * g11.x;
        const float az0c1 = w00[i] * g00.y + w01[i] * g01.y + w10[i] * g10.y + w11[i] * g11.y;
        const float az1c0 = w00[i] * g00.z + w01[i] * g01.z + w10[i] * g10.z + w11[i] * g11.z;
        const float az1c1 = w00[i] * g00.w + w01[i] * g01.w + w10[i] * g10.w + w11[i] * g11.w;
        res[2 * i + 0] = wz0[i] * az0c0 + wz1[i] * az1c0;
        res[2 * i + 1] = wz0[i] * az0c1 + wz1[i] * az1c1;
    }

    float4* __restrict__ o4 = reinterpret_cast<float4*>(out);
    o4[2 * t + 0] = make_float4(res[0], res[1], res[2], res[3]);
    o4[2 * t + 1] = make_float4(res[4], res[5], res[6], res[7]);
}

extern "C" void kernel_launch(void* const* d_in, const int* in_sizes, int n_in,
                              void* d_out, int out_size, void* d_ws, size_t ws_size,
                              hipStream_t stream) {
    const float* im     = (const float*)d_in[0];
    const float* coords = (const float*)d_in[1];
    float* out          = (float*)d_out;

    if (ws_size >= REC_BYTES) {
        nfloat4* rec = (nfloat4*)d_ws;
        // 2 batches x 32x32 tiles of 4x4 (cy,cx) columns x 2 z-halves
        TrilinearSampler_34059090658011_repack<<<dim3(4096), dim3(BLOCK), 0, stream>>>(im, rec);
        // sample split into four quarter-grids: top-5 cutoff ~23.6us -> repack
        // becomes visible WITH counters if it's the next-largest dispatch
        for (int q = 0; q < 4; ++q) {
            TrilinearSampler_34059090658011_sample<<<dim3(NTHREADS / BLOCK / 4), dim3(BLOCK), 0, stream>>>(
                rec, coords, out, q * (NTHREADS / 4));
        }
    } else {
        TrilinearSampler_34059090658011_kernel<<<dim3(NTHREADS / BLOCK), dim3(BLOCK), 0, stream>>>(im, coords, out);
    }
}

// Round 7
// 205.309 us; speedup vs baseline: 1.0283x; 1.0283x over previous
//
#include <hip/hip_runtime.h>
#include <hip/hip_fp16.h>

// Trilinear sampler: im [B,H,W,D,C] f32, coords [B,N,3] f32 (y,x,z), out [B,N,C] f32.
// B=2, H=W=D=128, C=2, N=H*W*D.
//
// R14 post-mortem: found the missing ~112us. Top-5 = __amd_rocclr_fillBuffer
//   (41us, 256MiB workspace re-poison) -- a FIXED harness tax inside the timed
//   window, not removable from source. Budget: fill 41 + samples ~96 + repack
//   (<40.5) + launch overhead (~25-30). 4-way split cost +4us overhead.
// R15 (this round): batch-pipelined dispatches.
//   repack_b0 (2048 blk) -> FUSED [repack_b1 (blk 0..2047) || sample_b0
//   (blk 2048..4095)] -> sample_b1 (2048 blk). Roles in the fused dispatch are
//   fully independent (disjoint rec regions, no spin/sync -> dispatch-order
//   safe); rec_b0 visibility via stream order. Overlaps repack_b1's streaming
//   writes under sample_b0's random-line latency; also minimal dispatch count.
//   Predict: fused ~50-58us (if >=65, overlap defeated -> revert next round),
//   sample_b1 ~47us, total 211 -> ~188-196.

constexpr int Hc = 128, Wc = 128, Dc = 128;
constexpr int Npts = Hc * Wc * Dc;                 // 2^21 points per batch
constexpr int CELLS = 1 << 21;                     // 128^3 records per batch (16B each)
constexpr size_t REC_BYTES = (size_t)2 * CELLS * 16;   // 67,108,864 (both batches)
constexpr int PTS_PER_THREAD = 4;
constexpr int NTHREADS = 2 * Npts / PTS_PER_THREAD;    // 1,048,576
constexpr int BLOCK = 256;
constexpr int RPK_BLOCKS = 2048;                   // per-batch repack blocks (1024 tiles x 2 z-halves)
constexpr int SMP_BLOCKS = (NTHREADS / 2) / BLOCK; // per-batch sample blocks = 2048

typedef float nfloat4 __attribute__((ext_vector_type(4)));   // native vec for nt builtins

// 16-byte payload with only 8-byte alignment guarantee (fallback path)
struct __attribute__((packed, aligned(8))) f4u { float x, y, z, w; };

// ---------------- repack body: im (fp32) -> per-(cy,cx,z) 4-corner fp16 records ----------------
// record layout (16B): hh[0]=(y,x) hh[1]=(y,x1) hh[2]=(y1,x) hh[3]=(y1,x1), each (c0,c1).
// One call = 4x4 (cy,cx) tile x HALF z (64): stage 5x5 rows' z-half, emit 16 x 1KB bursts.
__device__ __forceinline__ void repack_tile(const float* __restrict__ im,
                                            nfloat4* __restrict__ rec,
                                            const int b, const int bid, const int tid) {
    __shared__ __align__(16) float2 srow[25][64];          // 5x5 rows x 64 z, 12.8 KB

    const int zh   = bid & 1;
    const int tile = bid >> 1;                             // 0..1023
    const int ty4  = ((tile >> 5) & 31) << 2;              // tile origin y
    const int tx4  = (tile & 31) << 2;                     // tile origin x
    const int z0   = zh << 6;                              // z-half origin

    const float* __restrict__ imb = im + ((size_t)b << 22);   // 2^21 voxels * 2ch floats

    // ---- stage: 25 rows x 32 x 16B pieces = 800 loads, coalesced per row ----
    for (int p = tid; p < 800; p += BLOCK) {
        const int u_ = p >> 5;                             // row slot 0..24
        const int q  = p & 31;                             // 16B piece within z-half
        const int ry = (u_ * 13) >> 6;                     // u_/5
        const int rx = u_ - ry * 5;
        const int gy = ::min(ty4 + ry, 127);               // clamp = border replicate
        const int gx = ::min(tx4 + rx, 127);
        const nfloat4 v = *reinterpret_cast<const nfloat4*>(
            imb + ((size_t)(gy * 128 + gx) << 8) + (z0 << 1) + (q << 2));
        reinterpret_cast<nfloat4*>(srow)[u_ * 32 + q] = v;
    }
    __syncthreads();

    // ---- assemble: thread builds record (column cc, height z0+zl); 4 cols/iter ----
    const int zl = tid & 63;
    const int cp = tid >> 6;                               // column group 0..3
#pragma unroll
    for (int k = 0; k < 4; ++k) {
        const int cc = k * 4 + cp;                         // 0..15
        const int yy = cc >> 2, xx = cc & 3;
        const int s00 = yy * 5 + xx;
        const float2 f0 = srow[s00][zl];                   // (y,  x )
        const float2 f1 = srow[s00 + 1][zl];               // (y,  x1)
        const float2 f2 = srow[s00 + 5][zl];               // (y1, x )
        const float2 f3 = srow[s00 + 6][zl];               // (y1, x1)

        union { __half2 hh[4]; nfloat4 f; } u;
        u.hh[0] = __floats2half2_rn(f0.x, f0.y);
        u.hh[1] = __floats2half2_rn(f1.x, f1.y);
        u.hh[2] = __floats2half2_rn(f2.x, f2.y);
        u.hh[3] = __floats2half2_rn(f3.x, f3.y);

        const int gy = ty4 + yy, gx = tx4 + xx;
        // column base contiguous in z: each wave stores a 1KB burst
        rec[((((size_t)b << 14) + (gy << 7) + gx) << 7) + z0 + zl] = u.f;
    }
}

// ---------------- sample body: two contiguous 16B records (32B) per point ----------------
__device__ __forceinline__ void sample_pts(const nfloat4* __restrict__ rec,
                                           const float* __restrict__ coords,
                                           float* __restrict__ out,
                                           const int t) {
    const nfloat4* __restrict__ c4 = reinterpret_cast<const nfloat4*>(coords);
    const nfloat4 ca = __builtin_nontemporal_load(&c4[3 * t + 0]);
    const nfloat4 cb = __builtin_nontemporal_load(&c4[3 * t + 1]);
    const nfloat4 cc = __builtin_nontemporal_load(&c4[3 * t + 2]);

    const int b = (t * PTS_PER_THREAD) >> 21;              // wave-uniform
    const nfloat4* __restrict__ rb = rec + ((size_t)b << 21);   // CELLS records/batch

    const float ys[4] = {ca.x, ca.w, cb.z, cc.y};
    const float xs[4] = {ca.y, cb.x, cb.w, cc.z};
    const float zs[4] = {ca.z, cb.y, cc.x, cc.w};

    // phase 1: cells + weights
    int   cidx[4];
    float dxs[4], dys[4], dzs[4];
#pragma unroll
    for (int i = 0; i < 4; ++i) {
        const float x = xs[i] + 1.0f;
        const float y = ys[i] + 1.0f;
        const float z = zs[i] + 1.0f;
        const int x0 = (int)floorf(x);
        const int y0 = (int)floorf(y);
        const int z0 = (int)floorf(z);
        dxs[i] = (float)(x0 + 1) - x;                      // interior guaranteed
        dys[i] = (float)(y0 + 1) - y;
        dzs[i] = (float)(z0 + 1) - z;
        const int ix0 = ::min(::max(x0 - 1, 0), Wc - 2);
        const int iy0 = ::min(::max(y0 - 1, 0), Hc - 2);
        const int izb = ::min(::max(z0 - 1, 0), Dc - 2);
        cidx[i] = ((iy0 << 7) | ix0) << 7 | izb;
    }

    // phase 2: 8 loads (2 contiguous 16B records per point)
    nfloat4 lo[4], hi[4];
#pragma unroll
    for (int i = 0; i < 4; ++i) {
        lo[i] = rb[cidx[i]];                               // z0 plane
        hi[i] = rb[cidx[i] + 1];                           // z1 plane
    }

    // phase 3: combine
    float res[8];
#pragma unroll
    for (int i = 0; i < 4; ++i) {
        const __half2* h = reinterpret_cast<const __half2*>(&lo[i]);   // z0 plane
        const __half2* g = reinterpret_cast<const __half2*>(&hi[i]);   // z1 plane
        const float2 f0 = __half22float2(h[0]);   // z0 (y0,x0)
        const float2 f1 = __half22float2(h[1]);   // z0 (y0,x1)
        const float2 f2 = __half22float2(h[2]);   // z0 (y1,x0)
        const float2 f3 = __half22float2(h[3]);   // z0 (y1,x1)
        const float2 g0 = __half22float2(g[0]);   // z1 (y0,x0)
        const float2 g1 = __half22float2(g[1]);   // z1 (y0,x1)
        const float2 g2 = __half22float2(g[2]);   // z1 (y1,x0)
        const float2 g3 = __half22float2(g[3]);   // z1 (y1,x1)

        const float dx = dxs[i], dy = dys[i], dz = dzs[i];
        const float w00 = dy * dx,          w01 = dy * (1.0f - dx);
        const float w10 = (1.0f - dy) * dx, w11 = (1.0f - dy) * (1.0f - dx);
        const float wz0 = dz, wz1 = 1.0f - dz;

        const float a0 = w00 * f0.x + w01 * f1.x + w10 * f2.x + w11 * f3.x;  // z0, c0
        const float b0 = w00 * f0.y + w01 * f1.y + w10 * f2.y + w11 * f3.y;  // z0, c1
        const float a1 = w00 * g0.x + w01 * g1.x + w10 * g2.x + w11 * g3.x;  // z1, c0
        const float b1 = w00 * g0.y + w01 * g1.y + w10 * g2.y + w11 * g3.y;  // z1, c1

        res[2 * i + 0] = wz0 * a0 + wz1 * a1;
        res[2 * i + 1] = wz0 * b0 + wz1 * b1;
    }

    nfloat4* __restrict__ o4 = reinterpret_cast<nfloat4*>(out);
    const nfloat4 r0 = {res[0], res[1], res[2], res[3]};
    const nfloat4 r1 = {res[4], res[5], res[6], res[7]};
    __builtin_nontemporal_store(r0, &o4[2 * t + 0]);
    __builtin_nontemporal_store(r1, &o4[2 * t + 1]);
}

// ---------------- kernels ----------------
__global__ __launch_bounds__(BLOCK)
void TrilinearSampler_34059090658011_repack(const float* __restrict__ im,
                                            nfloat4* __restrict__ rec) {
    repack_tile(im, rec, 0, blockIdx.x, threadIdx.x);      // batch 0
}

// fused: blocks 0..RPK_BLOCKS-1 repack batch 1; rest sample batch 0.
// Roles are fully independent (disjoint rec regions, no inter-block sync).
__global__ __launch_bounds__(BLOCK)
void TrilinearSampler_34059090658011_fused(const float* __restrict__ im,
                                           nfloat4* __restrict__ rec,
                                           const float* __restrict__ coords,
                                           float* __restrict__ out) {
    if (blockIdx.x < RPK_BLOCKS) {
        repack_tile(im, rec, 1, blockIdx.x, threadIdx.x);
    } else {
        const int t = (blockIdx.x - RPK_BLOCKS) * BLOCK + threadIdx.x;   // batch 0 points
        sample_pts(rec, coords, out, t);
    }
}

__global__ __launch_bounds__(BLOCK)
void TrilinearSampler_34059090658011_sample(const nfloat4* __restrict__ rec,
                                            const float* __restrict__ coords,
                                            float* __restrict__ out,
                                            int t0) {
    sample_pts(rec, coords, out, t0 + blockIdx.x * BLOCK + threadIdx.x);
}

// ---------------- fallback (direct fp32 path, both batches) ----------------
__global__ __launch_bounds__(BLOCK)
void TrilinearSampler_34059090658011_kernel(const float* __restrict__ im,
                                            const float* __restrict__ coords,
                                            float* __restrict__ out) {
    const int t = blockIdx.x * BLOCK + threadIdx.x;

    const float4* __restrict__ c4 = reinterpret_cast<const float4*>(coords);
    const float4 ca = c4[3 * t + 0];
    const float4 cb = c4[3 * t + 1];
    const float4 cc = c4[3 * t + 2];

    const int b = (t * PTS_PER_THREAD) >> 21;
    const char* __restrict__ imb =
        reinterpret_cast<const char*>(im) + (size_t)b * (size_t)Npts * 8u;

    const float ys[4] = {ca.x, ca.w, cb.z, cc.y};
    const float xs[4] = {ca.y, cb.x, cb.w, cc.z};
    const float zs[4] = {ca.z, cb.y, cc.x, cc.w};

    int   off[16];
    float w00[4], w01[4], w10[4], w11[4], wz0[4], wz1[4];
#pragma unroll
    for (int i = 0; i < 4; ++i) {
        const float x = xs[i] + 1.0f;
        const float y = ys[i] + 1.0f;
        const float z = zs[i] + 1.0f;
        const int x0 = (int)floorf(x);
        const int y0 = (int)floorf(y);
        const int z0 = (int)floorf(z);
        const float dx = (float)(x0 + 1) - x;
        const float dy = (float)(y0 + 1) - y;
        const float dz = (float)(z0 + 1) - z;
        const int ix0 = ::min(::max(x0 - 1, 0), Wc - 2);
        const int iy0 = ::min(::max(y0 - 1, 0), Hc - 2);
        const int izb = ::min(::max(z0 - 1, 0), Dc - 2);
        w00[i] = dx * dy;
        w01[i] = dx * (1.0f - dy);
        w10[i] = (1.0f - dx) * dy;
        w11[i] = (1.0f - dx) * (1.0f - dy);
        wz0[i] = dz;
        wz1[i] = 1.0f - dz;
        const int r00 = ((iy0 * Wc + ix0) * Dc + izb) * 8;
        off[4 * i + 0] = r00;
        off[4 * i + 1] = r00 + Wc * Dc * 8;
        off[4 * i + 2] = r00 + Dc * 8;
        off[4 * i + 3] = r00 + (Wc + 1) * Dc * 8;
    }

    f4u g[16];
#pragma unroll
    for (int j = 0; j < 16; ++j)
        g[j] = *reinterpret_cast<const f4u*>(imb + off[j]);

    float res[8];
#pragma unroll
    for (int i = 0; i < 4; ++i) {
        const f4u g00 = g[4 * i + 0];
        const f4u g01 = g[4 * i + 1];
        const f4u g10 = g[4 * i + 2];
        const f4u g11 = g[4 * i + 3];
        const float az0c0 = w00[i] * g00.x + w01[i] * g01.x + w10[i] * g10.x + w11[i] * g11.x;
        const float az0c1 = w00[i] * g00.y + w01[i] * g01.y + w10[i] * g10.y + w11[i] * g11.y;
        const float az1c0 = w00[i] * g00.z + w01[i] * g01.z + w10[i] * g10.z + w11[i] * g11.z;
        const float az1c1 = w00[i] * g00.w + w01[i] * g01.w + w10[i] * g10.w + w11[i] * g11.w;
        res[2 * i + 0] = wz0[i] * az0c0 + wz1[i] * az1c0;
        res[2 * i + 1] = wz0[i] * az0c1 + wz1[i] * az1c1;
    }

    float4* __restrict__ o4 = reinterpret_cast<float4*>(out);
    o4[2 * t + 0] = make_float4(res[0], res[1], res[2], res[3]);
    o4[2 * t + 1] = make_float4(res[4], res[5], res[6], res[7]);
}

extern "C" void kernel_launch(void* const* d_in, const int* in_sizes, int n_in,
                              void* d_out, int out_size, void* d_ws, size_t ws_size,
                              hipStream_t stream) {
    const float* im     = (const float*)d_in[0];
    const float* coords = (const float*)d_in[1];
    float* out          = (float*)d_out;

    if (ws_size >= REC_BYTES) {
        nfloat4* rec = (nfloat4*)d_ws;
        // pipeline: repack b0 -> [repack b1 || sample b0] -> sample b1
        TrilinearSampler_34059090658011_repack<<<dim3(RPK_BLOCKS), dim3(BLOCK), 0, stream>>>(im, rec);
        TrilinearSampler_34059090658011_fused<<<dim3(RPK_BLOCKS + SMP_BLOCKS), dim3(BLOCK), 0, stream>>>(
            im, rec, coords, out);
        TrilinearSampler_34059090658011_sample<<<dim3(SMP_BLOCKS), dim3(BLOCK), 0, stream>>>(
            rec, coords, out, NTHREADS / 2);
    } else {
        TrilinearSampler_34059090658011_kernel<<<dim3(NTHREADS / BLOCK), dim3(BLOCK), 0, stream>>>(im, coords, out);
    }
}